// Round 2
// baseline (1972.670 us; speedup 1.0000x reference)
//
#include <hip/hip_runtime.h>
#include <hip/hip_bf16.h>

typedef __hip_bfloat16 bf16;
typedef __attribute__((ext_vector_type(8))) short v8s;   // 8 bf16 raw (4 VGPRs)
typedef __attribute__((ext_vector_type(4))) float v4f;   // MFMA C/D frag

#define MFMA(a, b, c) __builtin_amdgcn_mfma_f32_16x16x32_bf16((a), (b), (c), 0, 0, 0)

static constexpr int BB = 2, SEQ = 4096, HIDN = 2048, NH = 16, NKV = 4, HD = 128;
static constexpr float SCALE = 0.08838834764831845f;  // 128^-0.5
static constexpr float NEGV = -1e9f;

__device__ __forceinline__ bf16 f2b(float x) { return __float2bfloat16(x); }

// ---------------------------------------------------------------- fp32 -> bf16
__global__ void convert_k(const float* __restrict__ X, bf16* __restrict__ Y, long n) {
  long idx = (long)blockIdx.x * 256 + threadIdx.x;
  if (idx < n) Y[idx] = f2b(X[idx]);
}

// ---------------------------------------------------------------- transpose+cast
// Wt[n][k] = bf16(W[k][n]); coalesced writes, strided reads served by L2
__global__ void transpose_k(const float* __restrict__ W, bf16* __restrict__ Wt,
                            int K, int N) {
  long idx = (long)blockIdx.x * 256 + threadIdx.x;
  if (idx >= (long)K * N) return;
  int k = (int)(idx % K);
  int n = (int)(idx / K);
  Wt[idx] = f2b(W[(long)k * N + n]);
}

// ---------------------------------------------------------------- GEMM (B^T)
// C[M,N] = A[M,K] @ Bt[N,K]^T, bf16 in / fp32 acc / OT out.
// 64x64 C tile per 256-thread block; wave w owns rows 16w..16w+15 (4 16x16 tiles).
// A frag: row m=lane&15, k=quad*8+j. Bt frag: row n=lane&15, k=quad*8+j.
// MODE epilogue scatter: 0=row-major fp32, 1=Q[b][h][s][d], 2=K[b][kv][s][d],
//                        3=Vt[b][kv][d][s]  (1..3 write bf16)
template <int MODE, typename OT>
__global__ __launch_bounds__(256) void gemm_bt(const bf16* __restrict__ A,
                                               const bf16* __restrict__ Bt,
                                               OT* __restrict__ C,
                                               int M, int N, int K) {
  const int lane = threadIdx.x & 63, wv = threadIdx.x >> 6;
  const int l15 = lane & 15, quad = lane >> 4;
  const int m0 = blockIdx.y * 64, n0 = blockIdx.x * 64;

  const bf16* ap = A + (long)(m0 + wv * 16 + l15) * K + quad * 8;
  const bf16* bp = Bt + (long)(n0 + l15) * K + quad * 8;

  v4f acc[4] = {{0.f, 0.f, 0.f, 0.f}, {0.f, 0.f, 0.f, 0.f},
                {0.f, 0.f, 0.f, 0.f}, {0.f, 0.f, 0.f, 0.f}};

  for (int kc = 0; kc < K; kc += 32) {
    v8s af = *(const v8s*)(ap + kc);
#pragma unroll
    for (int t = 0; t < 4; t++) {
      v8s bfv = *(const v8s*)(bp + (long)t * 16 * K + kc);
      acc[t] = MFMA(af, bfv, acc[t]);
    }
  }

#pragma unroll
  for (int t = 0; t < 4; t++) {
#pragma unroll
    for (int r = 0; r < 4; r++) {
      int m = m0 + wv * 16 + quad * 4 + r;  // C row = quad*4+reg (verified layout)
      int n = n0 + t * 16 + l15;            // C col = lane&15
      long addr;
      if (MODE == 0) {
        addr = (long)m * N + n;
      } else {
        int bb = m >> 12, s = m & (SEQ - 1);
        int hh = n >> 7, d = n & (HD - 1);
        if (MODE == 1)      addr = ((long)(bb * NH + hh) * SEQ + s) * HD + d;
        else if (MODE == 2) addr = ((long)(bb * NKV + hh) * SEQ + s) * HD + d;
        else                addr = ((long)(bb * NKV + hh) * HD + d) * SEQ + s;
      }
      float v = acc[t][r];
      if constexpr (sizeof(OT) == 2) C[addr] = f2b(v);
      else                           C[addr] = v;
    }
  }
}

// ---------------------------------------------------------------- RoPE (in place)
// one thread per (row, d<64) pair; out1 = x1*c1 - x2*s1 ; out2 = x2*c2 + x1*s2
__global__ void rope_k(bf16* __restrict__ X, const float* __restrict__ cs,
                       const float* __restrict__ sn, int nheads) {
  int idx = blockIdx.x * 256 + threadIdx.x;
  int d = idx & 63;
  int row = idx >> 6;              // (b*nheads + h)*SEQ + s
  int s = row & (SEQ - 1);
  int bh = row >> 12;
  int b = bh / nheads;
  long xo = (long)row * HD;
  long co = ((long)b * SEQ + s) * HD;
  float x1 = __bfloat162float(X[xo + d]), x2 = __bfloat162float(X[xo + d + 64]);
  float c1 = cs[co + d], c2 = cs[co + d + 64];
  float s1 = sn[co + d], s2 = sn[co + d + 64];
  X[xo + d] = f2b(x1 * c1 - x2 * s1);
  X[xo + d + 64] = f2b(x2 * c2 + x1 * s2);
}

// ---------------------------------------------------------------- attention
// grid (64 qblocks, 16 heads, 2 batch), 256 threads. Wave wv owns q rows
// i*64+16wv .. +15. Keys: 4 local blocks (i-3..i) + 4 strided globals.
// S strip (16x512) in registers -> softmax -> P bf16 via LDS (2 halves) -> P@V.
__global__ __launch_bounds__(256) void attn_k(const bf16* __restrict__ Q,
                                              const bf16* __restrict__ K,
                                              const bf16* __restrict__ V,
                                              const float* __restrict__ msk,
                                              bf16* __restrict__ ctx) {
  const int i = blockIdx.x, h = blockIdx.y, b = blockIdx.z;
  const int kv = h >> 2;  // GQA: head h <- kv head h/4
  const int lane = threadIdx.x & 63, wv = threadIdx.x >> 6;
  const int l15 = lane & 15, quad = lane >> 4;

  // key-block table: kb[0..3] local windows w=0..3 (kb[3]==i self), kb[4..7] global
  int kb[8];
  bool kval[8];
#pragma unroll
  for (int w = 0; w < 4; w++) { kb[w] = i - 3 + w; kval[w] = (kb[w] >= 0); }
  {
    int st = i - 32; if (st < 0) st = 0;
    int n = i - st;
    int cnt = (n + 3) >> 2;  // ceil(n/4) strided candidates; keep last 4
#pragma unroll
    for (int t = 0; t < 4; t++) {
      int j = cnt + t - 4;
      kval[4 + t] = (j >= 0);
      kb[4 + t] = (j >= 0) ? (st + 4 * j) : 0;
    }
  }

  // Q fragments for this wave's 16 rows (4 k-chunks of 32)
  const bf16* qp = Q + ((long)(b * NH + h) * SEQ + i * 64 + wv * 16 + l15) * HD + quad * 8;
  v8s qf[4];
#pragma unroll
  for (int kk = 0; kk < 4; kk++) qf[kk] = *(const v8s*)(qp + kk * 32);

  // ---- S = Q K^T for 32 16x16 tiles (8 key blocks x 4 col tiles)
  v4f sacc[32];
#pragma unroll
  for (int kbi = 0; kbi < 8; kbi++) {
    if (kval[kbi]) {
      const bf16* kp = K + ((long)(b * NKV + kv) * SEQ + kb[kbi] * 64 + l15) * HD + quad * 8;
#pragma unroll
      for (int t = 0; t < 4; t++) {
        v4f a = {0.f, 0.f, 0.f, 0.f};
#pragma unroll
        for (int kk = 0; kk < 4; kk++)
          a = MFMA(qf[kk], *(const v8s*)(kp + (long)t * 16 * HD + kk * 32), a);
        sacc[kbi * 4 + t] = a;
      }
    } else {
#pragma unroll
      for (int t = 0; t < 4; t++) sacc[kbi * 4 + t] = {NEGV, NEGV, NEGV, NEGV};
    }
  }

  // ---- scale + masks (block validity, attention_mask_2d, intra-causal on self)
#pragma unroll
  for (int kbi = 0; kbi < 8; kbi++) {
    if (!kval[kbi]) continue;
#pragma unroll
    for (int t = 0; t < 4; t++) {
      int tok = kb[kbi] * 64 + t * 16 + l15;  // key token (== C col)
      float madd = (1.0f - msk[b * SEQ + tok]) * NEGV;
      v4f sv = sacc[kbi * 4 + t];
#pragma unroll
      for (int r = 0; r < 4; r++) {
        float x = sv[r] * SCALE + madd;
        if (kbi == 3) {  // self block: causal within block
          int kpp = t * 16 + l15;
          int qpp = wv * 16 + quad * 4 + r;
          if (kpp > qpp) x += NEGV;
        }
        sv[r] = x;
      }
      sacc[kbi * 4 + t] = sv;
    }
  }

  // ---- softmax over 512 cols; row r of quad in reg r, reduce over 16 lanes (l15)
  float rmax[4] = {-3.4e38f, -3.4e38f, -3.4e38f, -3.4e38f};
#pragma unroll
  for (int T = 0; T < 32; T++)
#pragma unroll
    for (int r = 0; r < 4; r++) rmax[r] = fmaxf(rmax[r], sacc[T][r]);
#pragma unroll
  for (int m = 1; m <= 8; m <<= 1)
#pragma unroll
    for (int r = 0; r < 4; r++) rmax[r] = fmaxf(rmax[r], __shfl_xor(rmax[r], m, 64));

  float rsum[4] = {0.f, 0.f, 0.f, 0.f};
#pragma unroll
  for (int T = 0; T < 32; T++)
#pragma unroll
    for (int r = 0; r < 4; r++) {
      float e = __expf(sacc[T][r] - rmax[r]);
      sacc[T][r] = e;
      rsum[r] += e;
    }
#pragma unroll
  for (int m = 1; m <= 8; m <<= 1)
#pragma unroll
    for (int r = 0; r < 4; r++) rsum[r] += __shfl_xor(rsum[r], m, 64);

  // ---- P (C-layout) -> LDS bf16 (A-layout) in two 256-col halves; P@V per half.
  // pb is per-wave; barriers only order the half phases. 33,792 B total.
  __shared__ __align__(16) bf16 pb[4][16][264];  // stride 264: 528 B, 16B-aligned
  v4f oacc[8] = {{0.f, 0.f, 0.f, 0.f}, {0.f, 0.f, 0.f, 0.f}, {0.f, 0.f, 0.f, 0.f},
                 {0.f, 0.f, 0.f, 0.f}, {0.f, 0.f, 0.f, 0.f}, {0.f, 0.f, 0.f, 0.f},
                 {0.f, 0.f, 0.f, 0.f}, {0.f, 0.f, 0.f, 0.f}};
  const bf16* vb0 = V + (long)(b * NKV + kv) * HD * SEQ;

#pragma unroll
  for (int half = 0; half < 2; half++) {
    __syncthreads();  // WAR: previous half's reads done before overwrite
#pragma unroll
    for (int kl = 0; kl < 4; kl++) {
      int T0 = (half * 4 + kl) * 4;
#pragma unroll
      for (int t = 0; t < 4; t++)
#pragma unroll
        for (int r = 0; r < 4; r++)
          pb[wv][quad * 4 + r][(kl * 4 + t) * 16 + l15] = f2b(sacc[T0 + t][r]);
    }
    __syncthreads();  // RAW: writes visible before reads
#pragma unroll
    for (int kl = 0; kl < 4; kl++) {
      int kbi = half * 4 + kl;
      if (!kval[kbi]) continue;  // P==0 there; skip is exact and avoids OOB V reads
#pragma unroll
      for (int hf = 0; hf < 2; hf++) {
        v8s af = *(const v8s*)&pb[wv][l15][kl * 64 + hf * 32 + quad * 8];
        int ktok = kb[kbi] * 64 + hf * 32 + quad * 8;
#pragma unroll
        for (int nt = 0; nt < 8; nt++) {
          const bf16* vp = vb0 + (long)(nt * 16 + l15) * SEQ + ktok;
          oacc[nt] = MFMA(af, *(const v8s*)vp, oacc[nt]);
        }
      }
    }
  }

  // ---- normalize + write ctx[b][s][h*128+d]
  const int tokw = i * 64 + wv * 16 + quad * 4;
#pragma unroll
  for (int nt = 0; nt < 8; nt++)
#pragma unroll
    for (int r = 0; r < 4; r++) {
      float v = oacc[nt][r] / rsum[r];
      long addr = ((long)b * SEQ + tokw + r) * (NH * HD) + h * HD + nt * 16 + l15;
      ctx[addr] = f2b(v);
    }
}

// ---------------------------------------------------------------- launch
extern "C" void kernel_launch(void* const* d_in, const int* in_sizes, int n_in,
                              void* d_out, int out_size, void* d_ws, size_t ws_size,
                              hipStream_t stream) {
  const float* hs  = (const float*)d_in[0];
  const float* cs  = (const float*)d_in[1];
  const float* sn  = (const float*)d_in[2];
  const float* msk = (const float*)d_in[3];
  const float* Wq  = (const float*)d_in[4];
  const float* Wk  = (const float*)d_in[5];
  const float* Wv  = (const float*)d_in[6];
  const float* Wo  = (const float*)d_in[7];
  float* out = (float*)d_out;

  char* w = (char*)d_ws;
  bf16* hsb = (bf16*)w; w += (size_t)BB * SEQ * HIDN * 2;       // 33.5 MB
  bf16* Wqt = (bf16*)w; w += (size_t)2048 * 2048 * 2;           //  8.4 MB
  bf16* Wkt = (bf16*)w; w += (size_t)512 * 2048 * 2;            //  2.1 MB
  bf16* Wvt = (bf16*)w; w += (size_t)512 * 2048 * 2;            //  2.1 MB
  bf16* Wot = (bf16*)w; w += (size_t)2048 * 2048 * 2;           //  8.4 MB
  bf16* Qr  = (bf16*)w; w += (size_t)BB * NH * SEQ * HD * 2;    // 33.5 MB
  bf16* Kr  = (bf16*)w; w += (size_t)BB * NKV * SEQ * HD * 2;   //  8.4 MB
  bf16* Vt  = (bf16*)w; w += (size_t)BB * NKV * HD * SEQ * 2;   //  8.4 MB
  bf16* ctx = hsb;  // hsb dead after V-proj; attn writes ctx after (stream-ordered)
  // total ws use: ~105 MB

  long nhs = (long)BB * SEQ * HIDN;
  convert_k<<<(nhs + 255) / 256, 256, 0, stream>>>(hs, hsb, nhs);

  transpose_k<<<(2048 * 2048) / 256, 256, 0, stream>>>(Wq, Wqt, 2048, 2048);
  transpose_k<<<(2048 * 512) / 256, 256, 0, stream>>>(Wk, Wkt, 2048, 512);
  transpose_k<<<(2048 * 512) / 256, 256, 0, stream>>>(Wv, Wvt, 2048, 512);
  transpose_k<<<(2048 * 2048) / 256, 256, 0, stream>>>(Wo, Wot, 2048, 2048);

  gemm_bt<1, bf16><<<dim3(2048 / 64, 8192 / 64), 256, 0, stream>>>(hsb, Wqt, Qr, 8192, 2048, 2048);
  gemm_bt<2, bf16><<<dim3(512 / 64, 8192 / 64), 256, 0, stream>>>(hsb, Wkt, Kr, 8192, 512, 2048);
  gemm_bt<3, bf16><<<dim3(512 / 64, 8192 / 64), 256, 0, stream>>>(hsb, Wvt, Vt, 8192, 512, 2048);

  rope_k<<<(BB * NH * SEQ * 64) / 256, 256, 0, stream>>>(Qr, cs, sn, NH);
  rope_k<<<(BB * NKV * SEQ * 64) / 256, 256, 0, stream>>>(Kr, cs, sn, NKV);

  attn_k<<<dim3(64, 16, 2), 256, 0, stream>>>(Qr, Kr, Vt, msk, ctx);

  gemm_bt<0, float><<<dim3(2048 / 64, 8192 / 64), 256, 0, stream>>>(ctx, Wot, out, 8192, 2048, 2048);
}

// Round 4
// 850.943 us; speedup vs baseline: 2.3182x; 2.3182x over previous
//
#include <hip/hip_runtime.h>
#include <hip/hip_bf16.h>

typedef __hip_bfloat16 bf16;
typedef __attribute__((ext_vector_type(8))) short v8s;   // 8 bf16 raw (4 VGPRs)
typedef __attribute__((ext_vector_type(4))) float v4f;   // MFMA C/D frag

#define MFMA(a, b, c) __builtin_amdgcn_mfma_f32_16x16x32_bf16((a), (b), (c), 0, 0, 0)

static constexpr int BB = 2, SEQ = 4096, HIDN = 2048, NH = 16, NKV = 4, HD = 128;
static constexpr float SCALE = 0.08838834764831845f;  // 128^-0.5
static constexpr float NEGV = -1e9f;

__device__ __forceinline__ bf16 f2b(float x) { return __float2bfloat16(x); }

// async global->LDS, 16B per lane. ldst wave-uniform; lane i lands at ldst+i*16.
__device__ __forceinline__ void glds16(const bf16* g, bf16* l) {
  __builtin_amdgcn_global_load_lds(
      (const __attribute__((address_space(1))) unsigned int*)g,
      (__attribute__((address_space(3))) unsigned int*)l, 16, 0, 0);
}

// ---------------------------------------------------------------- fp32 -> bf16
__global__ void convert_k(const float* __restrict__ X, bf16* __restrict__ Y, long n) {
  long idx = (long)blockIdx.x * 256 + threadIdx.x;
  if (idx < n) Y[idx] = f2b(X[idx]);
}

// ---------------------------------------------------------------- transpose+cast
__global__ void transpose_k(const float* __restrict__ W, bf16* __restrict__ Wt,
                            int K, int N) {
  long idx = (long)blockIdx.x * 256 + threadIdx.x;
  if (idx >= (long)K * N) return;
  int k = (int)(idx % K);
  int n = (int)(idx / K);
  Wt[idx] = f2b(W[(long)k * N + n]);
}

// ---------------------------------------------------------------- GEMM (B^T)
// C[M,N] = A[M,K] @ Bt[N,K]^T, bf16 in / fp32 acc / OT out.
// 128x128 C tile, 256 threads = 4 waves (2x2), wave owns 64x64 (4x4 MFMA tiles).
// BK=32, DOUBLE-buffered LDS staged via global_load_lds w16; one barrier/iter;
// explicit s_waitcnt vmcnt(0) guarantees RAW (don't rely on compiler's barrier
// drain). 2-buffer distance + barrier chain makes WAR structurally impossible.
// MODE epilogue scatter: 0=row-major fp32, 1=Q[b][h][s][d], 2=K[b][kv][s][d],
//                        3=Vt[b][kv][d][s]  (1..3 write bf16)
template <int MODE, typename OT>
__global__ __launch_bounds__(256) void gemm128(const bf16* __restrict__ A,
                                               const bf16* __restrict__ Bt,
                                               OT* __restrict__ C,
                                               int M, int N, int K) {
  __shared__ __align__(16) bf16 As[2][128 * 32];  // [buf][row][k], 64 B/row
  __shared__ __align__(16) bf16 Bs[2][128 * 32];

  const int tid = threadIdx.x;
  const int lane = tid & 63, wv = tid >> 6;
  const int wr = wv >> 1, wc = wv & 1;
  const int l15 = lane & 15, quad = lane >> 4;
  const int m0 = blockIdx.y * 128, n0 = blockIdx.x * 128;

  // staging: lane covers row tid>>2 (+64 for 2nd call), 16B chunk tid&3
  const bf16* aSrc = A + (long)(m0 + (tid >> 2)) * K + (tid & 3) * 8;
  const bf16* bSrc = Bt + (long)(n0 + (tid >> 2)) * K + (tid & 3) * 8;
  const long rowStride = (long)64 * K;

  int aoff[4], boff[4];
#pragma unroll
  for (int t = 0; t < 4; t++) {
    aoff[t] = (wr * 64 + t * 16 + l15) * 32 + quad * 8;
    boff[t] = (wc * 64 + t * 16 + l15) * 32 + quad * 8;
  }

  v4f acc[4][4];
#pragma unroll
  for (int i = 0; i < 4; i++)
#pragma unroll
    for (int j = 0; j < 4; j++) acc[i][j] = {0.f, 0.f, 0.f, 0.f};

  const int nIter = K >> 5;
  for (int it = 0; it < nIter; ++it) {
    const int kc = it << 5;
    const int bsel = it & 1;
    bf16* aD = As[bsel] + wv * 512;  // wave-uniform LDS base
    bf16* bD = Bs[bsel] + wv * 512;
    glds16(aSrc + kc, aD);
    glds16(aSrc + rowStride + kc, aD + 2048);
    glds16(bSrc + kc, bD);
    glds16(bSrc + rowStride + kc, bD + 2048);
    asm volatile("s_waitcnt vmcnt(0)" ::: "memory");  // HW-level RAW guarantee
    __syncthreads();

    const bf16* Ab = As[bsel];
    const bf16* Bb = Bs[bsel];
    v8s af[4], bfv[4];
#pragma unroll
    for (int t = 0; t < 4; t++) {
      af[t] = *(const v8s*)(Ab + aoff[t]);
      bfv[t] = *(const v8s*)(Bb + boff[t]);
    }
#pragma unroll
    for (int i = 0; i < 4; i++)
#pragma unroll
      for (int j = 0; j < 4; j++) acc[i][j] = MFMA(af[i], bfv[j], acc[i][j]);
  }

#pragma unroll
  for (int i = 0; i < 4; i++)
#pragma unroll
    for (int j = 0; j < 4; j++)
#pragma unroll
      for (int r = 0; r < 4; r++) {
        int m = m0 + wr * 64 + i * 16 + quad * 4 + r;  // C row = quad*4+reg
        int n = n0 + wc * 64 + j * 16 + l15;           // C col = lane&15
        long addr;
        if (MODE == 0) {
          addr = (long)m * N + n;
        } else {
          int bb = m >> 12, s = m & (SEQ - 1);
          int hh = n >> 7, d = n & (HD - 1);
          if (MODE == 1)      addr = ((long)(bb * NH + hh) * SEQ + s) * HD + d;
          else if (MODE == 2) addr = ((long)(bb * NKV + hh) * SEQ + s) * HD + d;
          else                addr = ((long)(bb * NKV + hh) * HD + d) * SEQ + s;
        }
        float v = acc[i][j][r];
        if constexpr (sizeof(OT) == 2) C[addr] = f2b(v);
        else                           C[addr] = v;
      }
}

// ---------------------------------------------------------------- RoPE (in place)
__global__ void rope_k(bf16* __restrict__ X, const float* __restrict__ cs,
                       const float* __restrict__ sn, int nheads) {
  int idx = blockIdx.x * 256 + threadIdx.x;
  int d = idx & 63;
  int row = idx >> 6;              // (b*nheads + h)*SEQ + s
  int s = row & (SEQ - 1);
  int bh = row >> 12;
  int b = bh / nheads;
  long xo = (long)row * HD;
  long co = ((long)b * SEQ + s) * HD;
  float x1 = __bfloat162float(X[xo + d]), x2 = __bfloat162float(X[xo + d + 64]);
  float c1 = cs[co + d], c2 = cs[co + d + 64];
  float s1 = sn[co + d], s2 = sn[co + d + 64];
  X[xo + d] = f2b(x1 * c1 - x2 * s1);
  X[xo + d + 64] = f2b(x2 * c2 + x1 * s2);
}

// ---------------------------------------------------------------- attention
__global__ __launch_bounds__(256) void attn_k(const bf16* __restrict__ Q,
                                              const bf16* __restrict__ K,
                                              const bf16* __restrict__ V,
                                              const float* __restrict__ msk,
                                              bf16* __restrict__ ctx) {
  const int i = blockIdx.x, h = blockIdx.y, b = blockIdx.z;
  const int kv = h >> 2;  // GQA: head h <- kv head h/4
  const int lane = threadIdx.x & 63, wv = threadIdx.x >> 6;
  const int l15 = lane & 15, quad = lane >> 4;

  int kb[8];
  bool kval[8];
#pragma unroll
  for (int w = 0; w < 4; w++) { kb[w] = i - 3 + w; kval[w] = (kb[w] >= 0); }
  {
    int st = i - 32; if (st < 0) st = 0;
    int n = i - st;
    int cnt = (n + 3) >> 2;  // ceil(n/4) strided candidates; keep last 4
#pragma unroll
    for (int t = 0; t < 4; t++) {
      int j = cnt + t - 4;
      kval[4 + t] = (j >= 0);
      kb[4 + t] = (j >= 0) ? (st + 4 * j) : 0;
    }
  }

  const bf16* qp = Q + ((long)(b * NH + h) * SEQ + i * 64 + wv * 16 + l15) * HD + quad * 8;
  v8s qf[4];
#pragma unroll
  for (int kk = 0; kk < 4; kk++) qf[kk] = *(const v8s*)(qp + kk * 32);

  v4f sacc[32];
#pragma unroll
  for (int kbi = 0; kbi < 8; kbi++) {
    if (kval[kbi]) {
      const bf16* kp = K + ((long)(b * NKV + kv) * SEQ + kb[kbi] * 64 + l15) * HD + quad * 8;
#pragma unroll
      for (int t = 0; t < 4; t++) {
        v4f a = {0.f, 0.f, 0.f, 0.f};
#pragma unroll
        for (int kk = 0; kk < 4; kk++)
          a = MFMA(qf[kk], *(const v8s*)(kp + (long)t * 16 * HD + kk * 32), a);
        sacc[kbi * 4 + t] = a;
      }
    } else {
#pragma unroll
      for (int t = 0; t < 4; t++) sacc[kbi * 4 + t] = {NEGV, NEGV, NEGV, NEGV};
    }
  }

#pragma unroll
  for (int kbi = 0; kbi < 8; kbi++) {
    if (!kval[kbi]) continue;
#pragma unroll
    for (int t = 0; t < 4; t++) {
      int tok = kb[kbi] * 64 + t * 16 + l15;  // key token (== C col)
      float madd = (1.0f - msk[b * SEQ + tok]) * NEGV;
      v4f sv = sacc[kbi * 4 + t];
#pragma unroll
      for (int r = 0; r < 4; r++) {
        float x = sv[r] * SCALE + madd;
        if (kbi == 3) {  // self block: causal within block
          int kpp = t * 16 + l15;
          int qpp = wv * 16 + quad * 4 + r;
          if (kpp > qpp) x += NEGV;
        }
        sv[r] = x;
      }
      sacc[kbi * 4 + t] = sv;
    }
  }

  float rmax[4] = {-3.4e38f, -3.4e38f, -3.4e38f, -3.4e38f};
#pragma unroll
  for (int T = 0; T < 32; T++)
#pragma unroll
    for (int r = 0; r < 4; r++) rmax[r] = fmaxf(rmax[r], sacc[T][r]);
#pragma unroll
  for (int m = 1; m <= 8; m <<= 1)
#pragma unroll
    for (int r = 0; r < 4; r++) rmax[r] = fmaxf(rmax[r], __shfl_xor(rmax[r], m, 64));

  float rsum[4] = {0.f, 0.f, 0.f, 0.f};
#pragma unroll
  for (int T = 0; T < 32; T++)
#pragma unroll
    for (int r = 0; r < 4; r++) {
      float e = __expf(sacc[T][r] - rmax[r]);
      sacc[T][r] = e;
      rsum[r] += e;
    }
#pragma unroll
  for (int m = 1; m <= 8; m <<= 1)
#pragma unroll
    for (int r = 0; r < 4; r++) rsum[r] += __shfl_xor(rsum[r], m, 64);

  __shared__ __align__(16) bf16 pb[4][16][264];
  v4f oacc[8] = {{0.f, 0.f, 0.f, 0.f}, {0.f, 0.f, 0.f, 0.f}, {0.f, 0.f, 0.f, 0.f},
                 {0.f, 0.f, 0.f, 0.f}, {0.f, 0.f, 0.f, 0.f}, {0.f, 0.f, 0.f, 0.f},
                 {0.f, 0.f, 0.f, 0.f}, {0.f, 0.f, 0.f, 0.f}};
  const bf16* vb0 = V + (long)(b * NKV + kv) * HD * SEQ;

#pragma unroll
  for (int half = 0; half < 2; half++) {
    __syncthreads();  // WAR
#pragma unroll
    for (int kl = 0; kl < 4; kl++) {
      int T0 = (half * 4 + kl) * 4;
#pragma unroll
      for (int t = 0; t < 4; t++)
#pragma unroll
        for (int r = 0; r < 4; r++)
          pb[wv][quad * 4 + r][(kl * 4 + t) * 16 + l15] = f2b(sacc[T0 + t][r]);
    }
    __syncthreads();  // RAW
#pragma unroll
    for (int kl = 0; kl < 4; kl++) {
      int kbi = half * 4 + kl;
      if (!kval[kbi]) continue;  // P==0 there; skip is exact and avoids OOB
#pragma unroll
      for (int hf = 0; hf < 2; hf++) {
        v8s af = *(const v8s*)&pb[wv][l15][kl * 64 + hf * 32 + quad * 8];
        int ktok = kb[kbi] * 64 + hf * 32 + quad * 8;
#pragma unroll
        for (int nt = 0; nt < 8; nt++) {
          const bf16* vp = vb0 + (long)(nt * 16 + l15) * SEQ + ktok;
          oacc[nt] = MFMA(af, *(const v8s*)vp, oacc[nt]);
        }
      }
    }
  }

  const int tokw = i * 64 + wv * 16 + quad * 4;
#pragma unroll
  for (int nt = 0; nt < 8; nt++)
#pragma unroll
    for (int r = 0; r < 4; r++) {
      float v = oacc[nt][r] / rsum[r];
      long addr = ((long)b * SEQ + tokw + r) * (NH * HD) + h * HD + nt * 16 + l15;
      ctx[addr] = f2b(v);
    }
}

// ---------------------------------------------------------------- launch
extern "C" void kernel_launch(void* const* d_in, const int* in_sizes, int n_in,
                              void* d_out, int out_size, void* d_ws, size_t ws_size,
                              hipStream_t stream) {
  const float* hs  = (const float*)d_in[0];
  const float* cs  = (const float*)d_in[1];
  const float* sn  = (const float*)d_in[2];
  const float* msk = (const float*)d_in[3];
  const float* Wq  = (const float*)d_in[4];
  const float* Wk  = (const float*)d_in[5];
  const float* Wv  = (const float*)d_in[6];
  const float* Wo  = (const float*)d_in[7];
  float* out = (float*)d_out;

  char* w = (char*)d_ws;
  bf16* hsb = (bf16*)w; w += (size_t)BB * SEQ * HIDN * 2;       // 33.5 MB
  bf16* Wqt = (bf16*)w; w += (size_t)2048 * 2048 * 2;           //  8.4 MB
  bf16* Wkt = (bf16*)w; w += (size_t)512 * 2048 * 2;            //  2.1 MB
  bf16* Wvt = (bf16*)w; w += (size_t)512 * 2048 * 2;            //  2.1 MB
  bf16* Wot = (bf16*)w; w += (size_t)2048 * 2048 * 2;           //  8.4 MB
  bf16* Qr  = (bf16*)w; w += (size_t)BB * NH * SEQ * HD * 2;    // 33.5 MB
  bf16* Kr  = (bf16*)w; w += (size_t)BB * NKV * SEQ * HD * 2;   //  8.4 MB
  bf16* Vt  = (bf16*)w; w += (size_t)BB * NKV * HD * SEQ * 2;   //  8.4 MB
  bf16* ctx = hsb;  // hsb dead after V-proj; stream-ordered reuse
  // total ws use: ~105 MB

  long nhs = (long)BB * SEQ * HIDN;
  convert_k<<<(nhs + 255) / 256, 256, 0, stream>>>(hs, hsb, nhs);

  transpose_k<<<(2048 * 2048) / 256, 256, 0, stream>>>(Wq, Wqt, 2048, 2048);
  transpose_k<<<(2048 * 512) / 256, 256, 0, stream>>>(Wk, Wkt, 2048, 512);
  transpose_k<<<(2048 * 512) / 256, 256, 0, stream>>>(Wv, Wvt, 2048, 512);
  transpose_k<<<(2048 * 2048) / 256, 256, 0, stream>>>(Wo, Wot, 2048, 2048);

  gemm128<1, bf16><<<dim3(2048 / 128, 8192 / 128), 256, 0, stream>>>(hsb, Wqt, Qr, 8192, 2048, 2048);
  gemm128<2, bf16><<<dim3(512 / 128, 8192 / 128), 256, 0, stream>>>(hsb, Wkt, Kr, 8192, 512, 2048);
  gemm128<3, bf16><<<dim3(512 / 128, 8192 / 128), 256, 0, stream>>>(hsb, Wvt, Vt, 8192, 512, 2048);

  rope_k<<<(BB * NH * SEQ * 64) / 256, 256, 0, stream>>>(Qr, cs, sn, NH);
  rope_k<<<(BB * NKV * SEQ * 64) / 256, 256, 0, stream>>>(Kr, cs, sn, NKV);

  attn_k<<<dim3(64, 16, 2), 256, 0, stream>>>(Qr, Kr, Vt, msk, ctx);

  gemm128<0, float><<<dim3(2048 / 128, 8192 / 128), 256, 0, stream>>>(ctx, Wot, out, 8192, 2048, 2048);
}

// Round 5
// 646.991 us; speedup vs baseline: 3.0490x; 1.3152x over previous
//
#include <hip/hip_runtime.h>
#include <hip/hip_bf16.h>

typedef __hip_bfloat16 bf16;
typedef __attribute__((ext_vector_type(8))) short v8s;   // 8 bf16 raw (4 VGPRs)
typedef __attribute__((ext_vector_type(4))) float v4f;   // MFMA C/D frag

#define MFMA(a, b, c) __builtin_amdgcn_mfma_f32_16x16x32_bf16((a), (b), (c), 0, 0, 0)

static constexpr int BB = 2, SEQ = 4096, HIDN = 2048, NH = 16, NKV = 4, HD = 128;
static constexpr float SCALE = 0.08838834764831845f;  // 128^-0.5
static constexpr float NEGV = -1e9f;

__device__ __forceinline__ bf16 f2b(float x) { return __float2bfloat16(x); }

// async global->LDS, 16B per lane. ldst wave-uniform; lane i lands at ldst+i*16.
__device__ __forceinline__ void glds16(const bf16* g, bf16* l) {
  __builtin_amdgcn_global_load_lds(
      (const __attribute__((address_space(1))) unsigned int*)g,
      (__attribute__((address_space(3))) unsigned int*)l, 16, 0, 0);
}

// ---------------------------------------------------------------- fp32 -> bf16
__global__ void convert_k(const float* __restrict__ X, bf16* __restrict__ Y, long n) {
  long idx = (long)blockIdx.x * 256 + threadIdx.x;
  if (idx < n) Y[idx] = f2b(X[idx]);
}

// ---------------------------------------------------------------- transpose+cast
__global__ void transpose_k(const float* __restrict__ W, bf16* __restrict__ Wt,
                            int K, int N) {
  long idx = (long)blockIdx.x * 256 + threadIdx.x;
  if (idx >= (long)K * N) return;
  int k = (int)(idx % K);
  int n = (int)(idx / K);
  Wt[idx] = f2b(W[(long)k * N + n]);
}

// ---------------------------------------------------------------- GEMM (B^T)
// (unchanged from round 4 — replay-validated)
template <int MODE, typename OT>
__global__ __launch_bounds__(256) void gemm128(const bf16* __restrict__ A,
                                               const bf16* __restrict__ Bt,
                                               OT* __restrict__ C,
                                               int M, int N, int K) {
  __shared__ __align__(16) bf16 As[2][128 * 32];
  __shared__ __align__(16) bf16 Bs[2][128 * 32];

  const int tid = threadIdx.x;
  const int lane = tid & 63, wv = tid >> 6;
  const int wr = wv >> 1, wc = wv & 1;
  const int l15 = lane & 15, quad = lane >> 4;
  const int m0 = blockIdx.y * 128, n0 = blockIdx.x * 128;

  const bf16* aSrc = A + (long)(m0 + (tid >> 2)) * K + (tid & 3) * 8;
  const bf16* bSrc = Bt + (long)(n0 + (tid >> 2)) * K + (tid & 3) * 8;
  const long rowStride = (long)64 * K;

  int aoff[4], boff[4];
#pragma unroll
  for (int t = 0; t < 4; t++) {
    aoff[t] = (wr * 64 + t * 16 + l15) * 32 + quad * 8;
    boff[t] = (wc * 64 + t * 16 + l15) * 32 + quad * 8;
  }

  v4f acc[4][4];
#pragma unroll
  for (int i = 0; i < 4; i++)
#pragma unroll
    for (int j = 0; j < 4; j++) acc[i][j] = {0.f, 0.f, 0.f, 0.f};

  const int nIter = K >> 5;
  for (int it = 0; it < nIter; ++it) {
    const int kc = it << 5;
    const int bsel = it & 1;
    bf16* aD = As[bsel] + wv * 512;
    bf16* bD = Bs[bsel] + wv * 512;
    glds16(aSrc + kc, aD);
    glds16(aSrc + rowStride + kc, aD + 2048);
    glds16(bSrc + kc, bD);
    glds16(bSrc + rowStride + kc, bD + 2048);
    asm volatile("s_waitcnt vmcnt(0)" ::: "memory");
    __syncthreads();

    const bf16* Ab = As[bsel];
    const bf16* Bb = Bs[bsel];
    v8s af[4], bfv[4];
#pragma unroll
    for (int t = 0; t < 4; t++) {
      af[t] = *(const v8s*)(Ab + aoff[t]);
      bfv[t] = *(const v8s*)(Bb + boff[t]);
    }
#pragma unroll
    for (int i = 0; i < 4; i++)
#pragma unroll
      for (int j = 0; j < 4; j++) acc[i][j] = MFMA(af[i], bfv[j], acc[i][j]);
  }

#pragma unroll
  for (int i = 0; i < 4; i++)
#pragma unroll
    for (int j = 0; j < 4; j++)
#pragma unroll
      for (int r = 0; r < 4; r++) {
        int m = m0 + wr * 64 + i * 16 + quad * 4 + r;
        int n = n0 + wc * 64 + j * 16 + l15;
        long addr;
        if (MODE == 0) {
          addr = (long)m * N + n;
        } else {
          int bb = m >> 12, s = m & (SEQ - 1);
          int hh = n >> 7, d = n & (HD - 1);
          if (MODE == 1)      addr = ((long)(bb * NH + hh) * SEQ + s) * HD + d;
          else if (MODE == 2) addr = ((long)(bb * NKV + hh) * SEQ + s) * HD + d;
          else                addr = ((long)(bb * NKV + hh) * HD + d) * SEQ + s;
        }
        float v = acc[i][j][r];
        if constexpr (sizeof(OT) == 2) C[addr] = f2b(v);
        else                           C[addr] = v;
      }
}

// ---------------------------------------------------------------- RoPE (in place)
__global__ void rope_k(bf16* __restrict__ X, const float* __restrict__ cs,
                       const float* __restrict__ sn, int nheads) {
  int idx = blockIdx.x * 256 + threadIdx.x;
  int d = idx & 63;
  int row = idx >> 6;
  int s = row & (SEQ - 1);
  int bh = row >> 12;
  int b = bh / nheads;
  long xo = (long)row * HD;
  long co = ((long)b * SEQ + s) * HD;
  float x1 = __bfloat162float(X[xo + d]), x2 = __bfloat162float(X[xo + d + 64]);
  float c1 = cs[co + d], c2 = cs[co + d + 64];
  float s1 = sn[co + d], s2 = sn[co + d + 64];
  X[xo + d] = f2b(x1 * c1 - x2 * s1);
  X[xo + d + 64] = f2b(x2 * c2 + x1 * s2);
}

// ---------------------------------------------------------------- attention
// grid (256 = qblock*4 + row-slice, 4 kv, 2 batch), 256 thr. Wave = q-head of
// the GQA group (h = kv*4 + wv); all 4 waves share staged K/V blocks in LDS.
// Pass 1: loop 8 key blocks, double-buffered glds16 K staging (XOR-16 swizzle),
// accumulate S strip (16x512/wave) in regs. Softmax. Pass 2: loop 8 blocks,
// stage V (XOR-8 swizzle), P via per-wave LDS transpose, accumulate O.
__global__ __launch_bounds__(256) void attn_k(const bf16* __restrict__ Q,
                                              const bf16* __restrict__ K,
                                              const bf16* __restrict__ V,
                                              const float* __restrict__ msk,
                                              bf16* __restrict__ ctx) {
  const int i = blockIdx.x >> 2, j = blockIdx.x & 3;  // qblock, 16-row slice
  const int kv = blockIdx.y, b = blockIdx.z;
  const int lane = threadIdx.x & 63, wv = threadIdx.x >> 6;
  const int h = kv * 4 + wv;  // this wave's q-head
  const int l15 = lane & 15, quad = lane >> 4;

  // kvs: K block (64 tok x 128 d) in pass 1 / V block (128 d x 64 tok) in pass 2
  __shared__ __align__(16) bf16 kvs[2][8192];   // 32 KB, double-buffered
  __shared__ __align__(16) bf16 pb[4][16][72];  // per-wave P transpose, 9 KB

  // key-block table: kb[0..3] local (kb[3]==i self), kb[4..7] strided global
  int kb[8];
  bool kval[8];
#pragma unroll
  for (int w = 0; w < 4; w++) { kb[w] = i - 3 + w; kval[w] = (kb[w] >= 0); }
  {
    int st = i - 32; if (st < 0) st = 0;
    int n = i - st;
    int cnt = (n + 3) >> 2;
#pragma unroll
    for (int t = 0; t < 4; t++) {
      int jj = cnt + t - 4;
      kval[4 + t] = (jj >= 0);
      kb[4 + t] = (jj >= 0) ? (st + 4 * jj) : 0;
    }
  }
  int kbc[8];
#pragma unroll
  for (int t = 0; t < 8; t++) kbc[t] = kb[t] < 0 ? 0 : kb[t];  // clamped for staging

  // Q fragments: this wave's 16 q-rows
  const bf16* qp = Q + ((long)(b * NH + h) * SEQ + i * 64 + j * 16 + l15) * HD + quad * 8;
  v8s qf[4];
#pragma unroll
  for (int kk = 0; kk < 4; kk++) qf[kk] = *(const v8s*)(qp + kk * 32);

  // staging lane geometry (K): 4 rows/call, granule g' = lane&15, row = base+lr
  const int klr = lane >> 4, kgp = lane & 15;
  // staging lane geometry (V): 8 rows/call, granule g' = lane&7
  const int vlr = lane >> 3, vgp = lane & 7;

  const bf16* gk = K + (long)(b * NKV + kv) * SEQ * HD;
  const bf16* gv = V + (long)(b * NKV + kv) * HD * SEQ;

  // ---- pass 1: S = Q K^T
  v4f sacc[32];
#pragma unroll
  for (int T = 0; T < 32; T++) sacc[T] = {0.f, 0.f, 0.f, 0.f};

  for (int it = 0; it < 8; ++it) {
    const int bsel = it & 1;
    // stage K block kbc[it]: rows = tokens (64), 256 B/row, 16 granules,
    // LDS[row][g'] = K[row][g' ^ (row&15)]
    {
      const bf16* kbase = gk + (long)kbc[it] * 64 * HD;
#pragma unroll
      for (int c = 0; c < 4; c++) {
        int tl = wv * 16 + c * 4 + klr;           // token row 0..63
        int g = kgp ^ (tl & 15);
        glds16(kbase + (long)tl * HD + g * 8, kvs[bsel] + (wv * 16 + c * 4) * 128);
      }
    }
    asm volatile("s_waitcnt vmcnt(0)" ::: "memory");
    __syncthreads();

    const bf16* Kb = kvs[bsel];
#pragma unroll
    for (int t = 0; t < 4; t++) {
      v4f a = sacc[it * 4 + t];
#pragma unroll
      for (int kk = 0; kk < 4; kk++) {
        int off = (t * 16 + l15) * 128 + (((kk * 4 + quad) ^ l15) * 8);
        a = MFMA(qf[kk], *(const v8s*)(Kb + off), a);
      }
      sacc[it * 4 + t] = a;
    }
  }

  // ---- scale + masks (invalid block, attention_mask_2d, intra-causal on self)
#pragma unroll
  for (int kbi = 0; kbi < 8; kbi++) {
    if (!kval[kbi]) {
#pragma unroll
      for (int t = 0; t < 4; t++) sacc[kbi * 4 + t] = {NEGV, NEGV, NEGV, NEGV};
      continue;
    }
#pragma unroll
    for (int t = 0; t < 4; t++) {
      int tok = kb[kbi] * 64 + t * 16 + l15;
      float madd = (1.0f - msk[b * SEQ + tok]) * NEGV;
      v4f sv = sacc[kbi * 4 + t];
#pragma unroll
      for (int r = 0; r < 4; r++) {
        float x = sv[r] * SCALE + madd;
        if (kbi == 3) {  // self block: causal within block
          int kpp = t * 16 + l15;
          int qpp = j * 16 + quad * 4 + r;
          if (kpp > qpp) x += NEGV;
        }
        sv[r] = x;
      }
      sacc[kbi * 4 + t] = sv;
    }
  }

  // ---- softmax over 512 cols (reduce over the 16 l15 lanes)
  float rmax[4] = {-3.4e38f, -3.4e38f, -3.4e38f, -3.4e38f};
#pragma unroll
  for (int T = 0; T < 32; T++)
#pragma unroll
    for (int r = 0; r < 4; r++) rmax[r] = fmaxf(rmax[r], sacc[T][r]);
#pragma unroll
  for (int m = 1; m <= 8; m <<= 1)
#pragma unroll
    for (int r = 0; r < 4; r++) rmax[r] = fmaxf(rmax[r], __shfl_xor(rmax[r], m, 64));

  float rsum[4] = {0.f, 0.f, 0.f, 0.f};
#pragma unroll
  for (int T = 0; T < 32; T++)
#pragma unroll
    for (int r = 0; r < 4; r++) {
      float e = __expf(sacc[T][r] - rmax[r]);
      sacc[T][r] = e;
      rsum[r] += e;
    }
#pragma unroll
  for (int m = 1; m <= 8; m <<= 1)
#pragma unroll
    for (int r = 0; r < 4; r++) rsum[r] += __shfl_xor(rsum[r], m, 64);

  // ---- pass 2: O = P V  (V staged from Vt: rows = d (128), 128 B/row, 8 gran,
  // LDS[row][g'] = V[row][g' ^ (row&7)])
  v4f oacc[8] = {{0.f, 0.f, 0.f, 0.f}, {0.f, 0.f, 0.f, 0.f}, {0.f, 0.f, 0.f, 0.f},
                 {0.f, 0.f, 0.f, 0.f}, {0.f, 0.f, 0.f, 0.f}, {0.f, 0.f, 0.f, 0.f},
                 {0.f, 0.f, 0.f, 0.f}, {0.f, 0.f, 0.f, 0.f}};

  for (int it = 0; it < 8; ++it) {
    const int bsel = it & 1;
    {
      const bf16* vbase = gv + (long)kbc[it] * 64;  // token offset within d-rows
#pragma unroll
      for (int c = 0; c < 4; c++) {
        int row = wv * 32 + c * 8 + vlr;            // d row 0..127
        int g = vgp ^ (row & 7);
        glds16(vbase + (long)row * SEQ + g * 8, kvs[bsel] + (wv * 32 + c * 8) * 64);
      }
    }
    // P block -> per-wave LDS transpose (C-layout -> A-layout), overlaps DMA
#pragma unroll
    for (int t = 0; t < 4; t++)
#pragma unroll
      for (int r = 0; r < 4; r++)
        pb[wv][quad * 4 + r][t * 16 + l15] = f2b(sacc[it * 4 + t][r]);

    asm volatile("s_waitcnt vmcnt(0)" ::: "memory");
    __syncthreads();

    const bf16* Vb = kvs[bsel];
#pragma unroll
    for (int hf = 0; hf < 2; hf++) {
      v8s af = *(const v8s*)&pb[wv][l15][hf * 32 + quad * 8];
#pragma unroll
      for (int nt = 0; nt < 8; nt++) {
        int off = (nt * 16 + l15) * 64 + (((hf * 4 + quad) ^ (l15 & 7)) * 8);
        oacc[nt] = MFMA(af, *(const v8s*)(Vb + off), oacc[nt]);
      }
    }
  }

  // ---- normalize + write ctx[b][s][h*128+d]
  const int tokw = i * 64 + j * 16 + quad * 4;
#pragma unroll
  for (int nt = 0; nt < 8; nt++)
#pragma unroll
    for (int r = 0; r < 4; r++) {
      float v = oacc[nt][r] / rsum[r];
      long addr = ((long)b * SEQ + tokw + r) * (NH * HD) + h * HD + nt * 16 + l15;
      ctx[addr] = f2b(v);
    }
}

// ---------------------------------------------------------------- launch
extern "C" void kernel_launch(void* const* d_in, const int* in_sizes, int n_in,
                              void* d_out, int out_size, void* d_ws, size_t ws_size,
                              hipStream_t stream) {
  const float* hs  = (const float*)d_in[0];
  const float* cs  = (const float*)d_in[1];
  const float* sn  = (const float*)d_in[2];
  const float* msk = (const float*)d_in[3];
  const float* Wq  = (const float*)d_in[4];
  const float* Wk  = (const float*)d_in[5];
  const float* Wv  = (const float*)d_in[6];
  const float* Wo  = (const float*)d_in[7];
  float* out = (float*)d_out;

  char* w = (char*)d_ws;
  bf16* hsb = (bf16*)w; w += (size_t)BB * SEQ * HIDN * 2;       // 33.5 MB
  bf16* Wqt = (bf16*)w; w += (size_t)2048 * 2048 * 2;           //  8.4 MB
  bf16* Wkt = (bf16*)w; w += (size_t)512 * 2048 * 2;            //  2.1 MB
  bf16* Wvt = (bf16*)w; w += (size_t)512 * 2048 * 2;            //  2.1 MB
  bf16* Wot = (bf16*)w; w += (size_t)2048 * 2048 * 2;           //  8.4 MB
  bf16* Qr  = (bf16*)w; w += (size_t)BB * NH * SEQ * HD * 2;    // 33.5 MB
  bf16* Kr  = (bf16*)w; w += (size_t)BB * NKV * SEQ * HD * 2;   //  8.4 MB
  bf16* Vt  = (bf16*)w; w += (size_t)BB * NKV * HD * SEQ * 2;   //  8.4 MB
  bf16* ctx = hsb;  // hsb dead after V-proj; stream-ordered reuse
  // total ws use: ~105 MB

  long nhs = (long)BB * SEQ * HIDN;
  convert_k<<<(nhs + 255) / 256, 256, 0, stream>>>(hs, hsb, nhs);

  transpose_k<<<(2048 * 2048) / 256, 256, 0, stream>>>(Wq, Wqt, 2048, 2048);
  transpose_k<<<(2048 * 512) / 256, 256, 0, stream>>>(Wk, Wkt, 2048, 512);
  transpose_k<<<(2048 * 512) / 256, 256, 0, stream>>>(Wv, Wvt, 2048, 512);
  transpose_k<<<(2048 * 2048) / 256, 256, 0, stream>>>(Wo, Wot, 2048, 2048);

  gemm128<1, bf16><<<dim3(2048 / 128, 8192 / 128), 256, 0, stream>>>(hsb, Wqt, Qr, 8192, 2048, 2048);
  gemm128<2, bf16><<<dim3(512 / 128, 8192 / 128), 256, 0, stream>>>(hsb, Wkt, Kr, 8192, 512, 2048);
  gemm128<3, bf16><<<dim3(512 / 128, 8192 / 128), 256, 0, stream>>>(hsb, Wvt, Vt, 8192, 512, 2048);

  rope_k<<<(BB * NH * SEQ * 64) / 256, 256, 0, stream>>>(Qr, cs, sn, NH);
  rope_k<<<(BB * NKV * SEQ * 64) / 256, 256, 0, stream>>>(Kr, cs, sn, NKV);

  attn_k<<<dim3(256, 4, 2), 256, 0, stream>>>(Qr, Kr, Vt, msk, ctx);

  gemm128<0, float><<<dim3(2048 / 128, 8192 / 128), 256, 0, stream>>>(ctx, Wot, out, 8192, 2048, 2048);
}